// Round 3
// baseline (63.949 us; speedup 1.0000x reference)
//
#include <hip/hip_runtime.h>
#include <hip/hip_bf16.h>
#include <math.h>

#define BB 8
#define SS 512
#define EE 128
#define HH 16
#define DKK 8

// ---------------------------------------------------------------------------
// Quantum head epilogue: lanes of an 8-lane head group hold c = cos(angle),
// lane w = wire w. Returns PauliZ expectation:
//   w==0 : c1*c2*...*c7       (prefix-XOR wrap bit)
//   w>=1 : c0*c1*...*cw       (prefix-XOR up to wire w)
// 8-lane Hillis-Steele inclusive product scan, no LDS.
// ---------------------------------------------------------------------------
__device__ __forceinline__ float quantum_prod(float c, int w)
{
    float p = (w == 0) ? 1.0f : c;     // exclude wire0 from the scan
    float u = __shfl_up(p, 1, 8); p = (w >= 1) ? p * u : p;
    u       = __shfl_up(p, 2, 8); p = (w >= 2) ? p * u : p;
    u       = __shfl_up(p, 4, 8); p = (w >= 4) ? p * u : p;
    const float c0   = __shfl(c, 0, 8);   // c0
    const float full = __shfl(p, 7, 8);   // c1*...*c7
    return (w == 0) ? full : c0 * p;
}

// ---------------------------------------------------------------------------
// Kernel 1: QKV GEMM + bias + theta + quantum head; also initializes
// out = bo (bias) so kernel 2 can atomically accumulate into it.
// grid (256, 3): blockIdx.x = 16-row tile, blockIdx.y = matrix (q/k/v).
// block 256: col = t&127, rh = t>>7 (8 rows each). x rows via wave-uniform
// pointers (s_load); W columns coalesced vector loads.
// Output layout (B, H, S, 8).
// ---------------------------------------------------------------------------
__global__ __launch_bounds__(256) void k_qkvq(
    const float* __restrict__ x,
    const float* __restrict__ Wq, const float* __restrict__ bq,
    const float* __restrict__ Wk, const float* __restrict__ bk,
    const float* __restrict__ Wv, const float* __restrict__ bv,
    const float* __restrict__ theta, const float* __restrict__ bo,
    float* __restrict__ qh, float* __restrict__ kh, float* __restrict__ vh,
    float* __restrict__ out)
{
    const int t   = threadIdx.x;
    const int col = t & 127;
    const int rh  = __builtin_amdgcn_readfirstlane(t >> 7);
    const int m   = blockIdx.y;
    const int row0 = blockIdx.x * 16 + rh * 8;

    const float* __restrict__ W  = (m == 0) ? Wq : (m == 1) ? Wk : Wv;
    const float* __restrict__ bb = (m == 0) ? bq : (m == 1) ? bk : bv;
    float* __restrict__ outp     = (m == 0) ? qh : (m == 1) ? kh : vh;

    const float4* xb = (const float4*)(x + (size_t)row0 * 128);  // row r at xb[r*32 + k4]

    const float bias = bb[col];
    float acc[8];
    #pragma unroll
    for (int r = 0; r < 8; ++r) acc[r] = bias;

    #pragma unroll 2
    for (int k4 = 0; k4 < 32; ++k4) {
        const float w0 = W[(k4 * 4 + 0) * 128 + col];
        const float w1 = W[(k4 * 4 + 1) * 128 + col];
        const float w2 = W[(k4 * 4 + 2) * 128 + col];
        const float w3 = W[(k4 * 4 + 3) * 128 + col];
        #pragma unroll
        for (int r = 0; r < 8; ++r) {
            const float4 xv = xb[r * 32 + k4];
            acc[r] += xv.x * w0 + xv.y * w1 + xv.z * w2 + xv.w * w3;
        }
    }

    const float th = theta[col];   // theta (16,8) contiguous = 128 floats
    const int h = col >> 3;
    const int w = col & 7;

    #pragma unroll
    for (int r = 0; r < 8; ++r) {
        const float c = __cosf(acc[r] + th);
        const float res = quantum_prod(c, w);
        const int g  = row0 + r;
        const int b_ = g >> 9;
        const int s  = g & 511;
        outp[(size_t)b_ * 65536 + (size_t)h * 4096 + s * 8 + w] = res;
    }

    if (m == 0) {
        const float b0 = bo[col];
        #pragma unroll
        for (int r = 0; r < 8; ++r)
            out[(size_t)(row0 + r) * 128 + col] = b0;
    }
}

// ---------------------------------------------------------------------------
// Kernel 2: attention + fused output projection (atomic accumulate).
// grid 512 = (bh 0..127) x (q-chunk 0..3 of 128 rows); block 256 = 4 waves.
// K/V head (512x8 each) staged in LDS. Wave wv handles j-quarter
// [wv*128, wv*128+128) for all 128 q rows; lane owns 2 q rows (r*64+L).
// Single-pass softmax (|score/sqrt(8)| <= sqrt(8): no max subtraction).
// 4-way partials combined in LDS, normalized, then attnout @ Wo_h added
// into out with fp32 HW atomics (out pre-initialized to bo by kernel 1).
// LDS: 32KB kv + 24KB part + 6KB red = 62KB -> exactly 2 blocks/CU.
// ---------------------------------------------------------------------------
__global__ __launch_bounds__(256) void k_attn_out(
    const float* __restrict__ qh, const float* __restrict__ kh,
    const float* __restrict__ vh, const float* __restrict__ Wo,
    float* __restrict__ out)
{
    __shared__ float4 kk[1024];         // 512 rows x 2 float4
    __shared__ float4 vv[1024];
    __shared__ float  part[4][128][12]; // [wave][qrow][o0..7, den, pad]
    __shared__ float  red[128][12];     // reduced + normalized

    const int t  = threadIdx.x;
    const int L  = t & 63;
    const int wv = __builtin_amdgcn_readfirstlane(t >> 6);
    const int bh = blockIdx.x >> 2;          // b*16 + h
    const int q0 = (blockIdx.x & 3) * 128;
    const int h  = bh & 15;

    // stage K/V (1024 float4 each; 4 per thread)
    const float4* kg = (const float4*)kh + (size_t)bh * 1024;
    const float4* vg = (const float4*)vh + (size_t)bh * 1024;
    #pragma unroll
    for (int i = 0; i < 4; ++i) {
        kk[t + 256 * i] = kg[t + 256 * i];
        vv[t + 256 * i] = vg[t + 256 * i];
    }

    // q rows r*64+L, r = 0,1
    const float4* qg = (const float4*)qh + ((size_t)bh * 512 + q0) * 2;
    const float4 qa0 = qg[(0 * 64 + L) * 2];
    const float4 qb0 = qg[(0 * 64 + L) * 2 + 1];
    const float4 qa1 = qg[(1 * 64 + L) * 2];
    const float4 qb1 = qg[(1 * 64 + L) * 2 + 1];

    __syncthreads();

    float a00=0.f,a01=0.f,a02=0.f,a03=0.f,a04=0.f,a05=0.f,a06=0.f,a07=0.f;
    float a10=0.f,a11=0.f,a12=0.f,a13=0.f,a14=0.f,a15=0.f,a16=0.f,a17=0.f;
    float den0 = 0.f, den1 = 0.f;
    const float scale = 0.35355339059327373f;  // 1/sqrt(8)

    const float4* kbase = kk + wv * 256;
    const float4* vbase = vv + wv * 256;

    #pragma unroll 2
    for (int j = 0; j < 128; ++j) {
        const float4 k0 = kbase[2 * j];
        const float4 k1 = kbase[2 * j + 1];
        const float s0 = qa0.x*k0.x + qa0.y*k0.y + qa0.z*k0.z + qa0.w*k0.w
                       + qb0.x*k1.x + qb0.y*k1.y + qb0.z*k1.z + qb0.w*k1.w;
        const float s1 = qa1.x*k0.x + qa1.y*k0.y + qa1.z*k0.z + qa1.w*k0.w
                       + qb1.x*k1.x + qb1.y*k1.y + qb1.z*k1.z + qb1.w*k1.w;
        const float e0 = __expf(s0 * scale);
        const float e1 = __expf(s1 * scale);
        den0 += e0; den1 += e1;
        const float4 v0 = vbase[2 * j];
        const float4 v1 = vbase[2 * j + 1];
        a00 += e0 * v0.x; a01 += e0 * v0.y; a02 += e0 * v0.z; a03 += e0 * v0.w;
        a04 += e0 * v1.x; a05 += e0 * v1.y; a06 += e0 * v1.z; a07 += e0 * v1.w;
        a10 += e1 * v0.x; a11 += e1 * v0.y; a12 += e1 * v0.z; a13 += e1 * v0.w;
        a14 += e1 * v1.x; a15 += e1 * v1.y; a16 += e1 * v1.z; a17 += e1 * v1.w;
    }

    // write partials (aligned float4 x3, stride 12 floats = 48B)
    {
        float* p0 = &part[wv][0 * 64 + L][0];
        ((float4*)p0)[0] = make_float4(a00, a01, a02, a03);
        ((float4*)p0)[1] = make_float4(a04, a05, a06, a07);
        ((float4*)p0)[2] = make_float4(den0, 0.f, 0.f, 0.f);
        float* p1 = &part[wv][1 * 64 + L][0];
        ((float4*)p1)[0] = make_float4(a10, a11, a12, a13);
        ((float4*)p1)[1] = make_float4(a14, a15, a16, a17);
        ((float4*)p1)[2] = make_float4(den1, 0.f, 0.f, 0.f);
    }
    __syncthreads();

    // 4-way reduce: q = t>>1, half = t&1
    {
        const int q = t >> 1;
        if ((t & 1) == 0) {
            float4 s = make_float4(0.f, 0.f, 0.f, 0.f);
            float d = 0.f;
            #pragma unroll
            for (int wq = 0; wq < 4; ++wq) {
                const float4 v = *(const float4*)&part[wq][q][0];
                s.x += v.x; s.y += v.y; s.z += v.z; s.w += v.w;
                d += part[wq][q][8];
            }
            *(float4*)&red[q][0] = s;
            red[q][8] = d;
        } else {
            float4 s = make_float4(0.f, 0.f, 0.f, 0.f);
            #pragma unroll
            for (int wq = 0; wq < 4; ++wq) {
                const float4 v = *(const float4*)&part[wq][q][4];
                s.x += v.x; s.y += v.y; s.z += v.z; s.w += v.w;
            }
            *(float4*)&red[q][4] = s;
        }
    }
    __syncthreads();

    // normalize in place
    if (t < 128) {
        const float inv = 1.0f / red[t][8];
        float4 a = *(const float4*)&red[t][0];
        float4 b = *(const float4*)&red[t][4];
        a.x *= inv; a.y *= inv; a.z *= inv; a.w *= inv;
        b.x *= inv; b.y *= inv; b.z *= inv; b.w *= inv;
        *(float4*)&red[t][0] = a;
        *(float4*)&red[t][4] = b;
    }
    __syncthreads();

    // fused output projection: attnout(128x8) @ Wo_h(8x128), atomic add.
    {
        const int col = t & 127;
        const int rg  = t >> 7;          // 0,1 -> rows rg*64..rg*64+63
        float wo[8];
        #pragma unroll
        for (int i = 0; i < 8; ++i)
            wo[i] = Wo[(h * 8 + i) * 128 + col];
        const int b_ = bh >> 4;
        float* obase = out + ((size_t)(b_ * 512 + q0 + rg * 64)) * 128 + col;
        for (int rr = 0; rr < 64; ++rr) {
            const float4 o0 = *(const float4*)&red[rg * 64 + rr][0];
            const float4 o1 = *(const float4*)&red[rg * 64 + rr][4];
            const float acc = o0.x*wo[0] + o0.y*wo[1] + o0.z*wo[2] + o0.w*wo[3]
                            + o1.x*wo[4] + o1.y*wo[5] + o1.z*wo[6] + o1.w*wo[7];
            unsafeAtomicAdd(obase + (size_t)rr * 128, acc);
        }
    }
}

// ---------------------------------------------------------------------------
extern "C" void kernel_launch(void* const* d_in, const int* in_sizes, int n_in,
                              void* d_out, int out_size, void* d_ws, size_t ws_size,
                              hipStream_t stream)
{
    const float* x     = (const float*)d_in[0];
    const float* Wq    = (const float*)d_in[1];
    const float* bq    = (const float*)d_in[2];
    const float* Wk    = (const float*)d_in[3];
    const float* bk    = (const float*)d_in[4];
    const float* Wv    = (const float*)d_in[5];
    const float* bv    = (const float*)d_in[6];
    const float* Wo    = (const float*)d_in[7];
    const float* bo    = (const float*)d_in[8];
    const float* theta = (const float*)d_in[9];
    float* out = (float*)d_out;

    float* ws = (float*)d_ws;
    float* qh = ws;                  // B*H*S*8 = 524288 floats each
    float* kh = ws + 524288;
    float* vh = ws + 1048576;

    k_qkvq<<<dim3(256, 3), 256, 0, stream>>>(x, Wq, bq, Wk, bk, Wv, bv,
                                             theta, bo, qh, kh, vh, out);
    k_attn_out<<<512, 256, 0, stream>>>(qh, kh, vh, Wo, out);
}

// Round 4
// 52.340 us; speedup vs baseline: 1.2218x; 1.2218x over previous
//
#include <hip/hip_runtime.h>
#include <hip/hip_bf16.h>
#include <math.h>

#define BB 8
#define SS 512
#define EE 128
#define HH 16
#define DKK 8

#define FMA4(ACC, S, W) do { (ACC).x += (S)*(W).x; (ACC).y += (S)*(W).y; \
                             (ACC).z += (S)*(W).z; (ACC).w += (S)*(W).w; } while(0)

// ---------------------------------------------------------------------------
// Kernel 1: QKV GEMM + bias + theta + quantum head.
// grid (256, 3): blockIdx.x = 16-row tile of x, blockIdx.y = matrix (q/k/v).
// block 256 = 4 waves. Per-lane tile: 2 rows x 4 cols.
//   cg = t&31 (col-group, col0 = cg*4), rg = t>>5 (row-group, rows rg*2,+1).
// x tile staged in LDS (8KB), read as 2-way-broadcast ds_read_b128;
// W read as coalesced global float4 (no SMEM, no scalar streaming).
// Quantum head: lane pair (even: wires 0-3, odd: wires 4-7) exchanges one
// product via shfl_xor(1). Output layout (B, H, S, 8).
// ---------------------------------------------------------------------------
__global__ __launch_bounds__(256) void k_qkvq(
    const float* __restrict__ x,
    const float* __restrict__ Wq, const float* __restrict__ bq,
    const float* __restrict__ Wk, const float* __restrict__ bk,
    const float* __restrict__ Wv, const float* __restrict__ bv,
    const float* __restrict__ theta,
    float* __restrict__ qh, float* __restrict__ kh, float* __restrict__ vh)
{
    __shared__ float xs[16][128];
    const int t = threadIdx.x;
    const int m = blockIdx.y;
    const int row0 = blockIdx.x * 16;

    // stage x tile (2048 floats = 512 float4)
    {
        const float4* xv = (const float4*)(x + (size_t)row0 * 128);
        float4* xsv = (float4*)&xs[0][0];
        xsv[t]       = xv[t];
        xsv[t + 256] = xv[t + 256];
    }
    __syncthreads();

    const int cg   = t & 31;
    const int col0 = cg * 4;
    const int rg   = t >> 5;          // 0..7
    const int r0   = rg * 2;

    const float* __restrict__ W  = (m == 0) ? Wq : (m == 1) ? Wk : Wv;
    const float* __restrict__ bb = (m == 0) ? bq : (m == 1) ? bk : bv;
    float* __restrict__ outp     = (m == 0) ? qh : (m == 1) ? kh : vh;

    float4 acc0 = *(const float4*)&bb[col0];
    float4 acc1 = acc0;

    #pragma unroll 4
    for (int k4 = 0; k4 < 32; ++k4) {
        const float4 xa = ((const float4*)xs[r0 + 0])[k4];
        const float4 xb = ((const float4*)xs[r0 + 1])[k4];
        const float4 w0 = *(const float4*)&W[(k4 * 4 + 0) * 128 + col0];
        const float4 w1 = *(const float4*)&W[(k4 * 4 + 1) * 128 + col0];
        const float4 w2 = *(const float4*)&W[(k4 * 4 + 2) * 128 + col0];
        const float4 w3 = *(const float4*)&W[(k4 * 4 + 3) * 128 + col0];
        FMA4(acc0, xa.x, w0); FMA4(acc0, xa.y, w1);
        FMA4(acc0, xa.z, w2); FMA4(acc0, xa.w, w3);
        FMA4(acc1, xb.x, w0); FMA4(acc1, xb.y, w1);
        FMA4(acc1, xb.z, w2); FMA4(acc1, xb.w, w3);
    }

    const float4 th = *(const float4*)&theta[col0];
    const int h    = cg >> 1;
    const int half = cg & 1;          // 0: wires 0-3, 1: wires 4-7

    float4 accs[2] = {acc0, acc1};
    #pragma unroll
    for (int r = 0; r < 2; ++r) {
        float4 c;
        c.x = __cosf(accs[r].x + th.x);
        c.y = __cosf(accs[r].y + th.y);
        c.z = __cosf(accs[r].z + th.z);
        c.w = __cosf(accs[r].w + th.w);
        // inclusive prefix products of this lane's 4 cosines
        const float p0 = c.x;
        const float p1 = p0 * c.y;
        const float p2 = p1 * c.z;
        const float p3 = p2 * c.w;
        // exchange full 4-products between the half-lanes of this head
        const float recv = __shfl_xor(p3, 1);
        float4 o;
        if (half == 0) {
            // wires 0..3: out0 = c1c2c3 * (c4..c7); outw = c0..cw
            const float s123 = c.y * c.z * c.w;
            o.x = s123 * recv;   // wire 0
            o.y = p1;            // wire 1
            o.z = p2;            // wire 2
            o.w = p3;            // wire 3
        } else {
            // wires 4..7: outw = (c0..c3) * (c4..cw)
            o.x = recv * p0;     // wire 4
            o.y = recv * p1;     // wire 5
            o.z = recv * p2;     // wire 6
            o.w = recv * p3;     // wire 7
        }
        const int g  = row0 + r0 + r;
        const int b_ = g >> 9;
        const int s  = g & 511;
        *(float4*)&outp[(((size_t)b_ * HH + h) * SS + s) * DKK + half * 4] = o;
    }
}

// ---------------------------------------------------------------------------
// Kernel 2: attention. grid 256 = (bh 0..127) x (q-half 0..1 of 256 rows).
// block 256 = 4 waves; wave wv covers j-quarter [wv*128,+128) for all 256
// q rows; lane owns R=4 q rows (L, L+64, L+128, L+192). K/V head staged in
// LDS (32KB), read as broadcast ds_read_b128 (amortized over 4 rows).
// Single-pass softmax (|score/sqrt(8)| <= sqrt(8), no max). 4-way partials
// combined in LDS (48KB buffer UNIONED with the K/V stage), normalized,
// written to hid (B,S,E).
// ---------------------------------------------------------------------------
__global__ __launch_bounds__(256) void k_attn(
    const float* __restrict__ qh, const float* __restrict__ kh,
    const float* __restrict__ vh, float* __restrict__ hid)
{
    __shared__ float smem[12288];                 // 48KB, dual-purpose
    float4* kk = (float4*)smem;                   // [1024] = K: 512 rows x 2
    float4* vv = (float4*)smem + 1024;            // [1024] = V
    float (*part)[256][12] = (float (*)[256][12])smem;  // [4][256][12] after j-loop

    const int t  = threadIdx.x;
    const int L  = t & 63;
    const int wv = __builtin_amdgcn_readfirstlane(t >> 6);
    const int bh = blockIdx.x >> 1;               // b*16 + h
    const int q0 = (blockIdx.x & 1) * 256;
    const int h  = bh & 15;
    const int b_ = bh >> 4;

    // stage K/V (1024 float4 each; 8 per thread)
    {
        const float4* kg = (const float4*)kh + (size_t)bh * 1024;
        const float4* vg = (const float4*)vh + (size_t)bh * 1024;
        #pragma unroll
        for (int i = 0; i < 4; ++i) {
            kk[t + 256 * i] = kg[t + 256 * i];
            vv[t + 256 * i] = vg[t + 256 * i];
        }
    }

    // q rows L + rr*64, rr = 0..3
    float4 qa[4], qb[4];
    {
        const float4* qg = (const float4*)qh + ((size_t)bh * 512 + q0) * 2;
        #pragma unroll
        for (int rr = 0; rr < 4; ++rr) {
            qa[rr] = qg[(rr * 64 + L) * 2];
            qb[rr] = qg[(rr * 64 + L) * 2 + 1];
        }
    }
    __syncthreads();

    float4 accA[4], accB[4];
    float  den[4];
    #pragma unroll
    for (int rr = 0; rr < 4; ++rr) {
        accA[rr] = make_float4(0.f, 0.f, 0.f, 0.f);
        accB[rr] = make_float4(0.f, 0.f, 0.f, 0.f);
        den[rr]  = 0.f;
    }
    const float scale = 0.35355339059327373f;     // 1/sqrt(8)
    const float4* kbase = kk + wv * 256;
    const float4* vbase = vv + wv * 256;

    #pragma unroll 2
    for (int j = 0; j < 128; ++j) {
        const float4 k0 = kbase[2 * j];
        const float4 k1 = kbase[2 * j + 1];
        const float4 v0 = vbase[2 * j];
        const float4 v1 = vbase[2 * j + 1];
        #pragma unroll
        for (int rr = 0; rr < 4; ++rr) {
            const float s = qa[rr].x*k0.x + qa[rr].y*k0.y + qa[rr].z*k0.z + qa[rr].w*k0.w
                          + qb[rr].x*k1.x + qb[rr].y*k1.y + qb[rr].z*k1.z + qb[rr].w*k1.w;
            const float e = __expf(s * scale);
            den[rr] += e;
            FMA4(accA[rr], e, v0);
            FMA4(accB[rr], e, v1);
        }
    }
    __syncthreads();   // K/V stage dead; smem becomes the partial buffer

    #pragma unroll
    for (int rr = 0; rr < 4; ++rr) {
        float* p = &part[wv][rr * 64 + L][0];
        ((float4*)p)[0] = accA[rr];
        ((float4*)p)[1] = accB[rr];
        p[8] = den[rr];
    }
    __syncthreads();

    // combine: thread t owns q-row t
    {
        float4 rA = make_float4(0.f, 0.f, 0.f, 0.f);
        float4 rB = make_float4(0.f, 0.f, 0.f, 0.f);
        float  rd = 0.f;
        #pragma unroll
        for (int wq = 0; wq < 4; ++wq) {
            const float* p = &part[wq][t][0];
            const float4 a = ((const float4*)p)[0];
            const float4 b = ((const float4*)p)[1];
            rA.x += a.x; rA.y += a.y; rA.z += a.z; rA.w += a.w;
            rB.x += b.x; rB.y += b.y; rB.z += b.z; rB.w += b.w;
            rd   += p[8];
        }
        const float inv = 1.0f / rd;
        rA.x *= inv; rA.y *= inv; rA.z *= inv; rA.w *= inv;
        rB.x *= inv; rB.y *= inv; rB.z *= inv; rB.w *= inv;
        float* o = hid + ((size_t)(b_ * 512 + q0 + t)) * 128 + h * 8;
        ((float4*)o)[0] = rA;
        ((float4*)o)[1] = rB;
    }
}

// ---------------------------------------------------------------------------
// Kernel 3: output projection hid(4096x128) @ Wo(128x128) + bo.
// Same structure as k_qkvq's GEMM (2 rows x 4 cols per lane), grid 256.
// ---------------------------------------------------------------------------
__global__ __launch_bounds__(256) void k_out(
    const float* __restrict__ hid, const float* __restrict__ Wo,
    const float* __restrict__ bo, float* __restrict__ out)
{
    __shared__ float hs[16][128];
    const int t = threadIdx.x;
    const int row0 = blockIdx.x * 16;

    {
        const float4* hv = (const float4*)(hid + (size_t)row0 * 128);
        float4* hsv = (float4*)&hs[0][0];
        hsv[t]       = hv[t];
        hsv[t + 256] = hv[t + 256];
    }
    __syncthreads();

    const int cg   = t & 31;
    const int col0 = cg * 4;
    const int rg   = t >> 5;
    const int r0   = rg * 2;

    float4 acc0 = *(const float4*)&bo[col0];
    float4 acc1 = acc0;

    #pragma unroll 4
    for (int k4 = 0; k4 < 32; ++k4) {
        const float4 xa = ((const float4*)hs[r0 + 0])[k4];
        const float4 xb = ((const float4*)hs[r0 + 1])[k4];
        const float4 w0 = *(const float4*)&Wo[(k4 * 4 + 0) * 128 + col0];
        const float4 w1 = *(const float4*)&Wo[(k4 * 4 + 1) * 128 + col0];
        const float4 w2 = *(const float4*)&Wo[(k4 * 4 + 2) * 128 + col0];
        const float4 w3 = *(const float4*)&Wo[(k4 * 4 + 3) * 128 + col0];
        FMA4(acc0, xa.x, w0); FMA4(acc0, xa.y, w1);
        FMA4(acc0, xa.z, w2); FMA4(acc0, xa.w, w3);
        FMA4(acc1, xb.x, w0); FMA4(acc1, xb.y, w1);
        FMA4(acc1, xb.z, w2); FMA4(acc1, xb.w, w3);
    }

    *(float4*)&out[(size_t)(row0 + r0 + 0) * 128 + col0] = acc0;
    *(float4*)&out[(size_t)(row0 + r0 + 1) * 128 + col0] = acc1;
}

// ---------------------------------------------------------------------------
extern "C" void kernel_launch(void* const* d_in, const int* in_sizes, int n_in,
                              void* d_out, int out_size, void* d_ws, size_t ws_size,
                              hipStream_t stream)
{
    const float* x     = (const float*)d_in[0];
    const float* Wq    = (const float*)d_in[1];
    const float* bq    = (const float*)d_in[2];
    const float* Wk    = (const float*)d_in[3];
    const float* bk    = (const float*)d_in[4];
    const float* Wv    = (const float*)d_in[5];
    const float* bv    = (const float*)d_in[6];
    const float* Wo    = (const float*)d_in[7];
    const float* bo    = (const float*)d_in[8];
    const float* theta = (const float*)d_in[9];
    float* out = (float*)d_out;

    float* ws  = (float*)d_ws;
    float* qh  = ws;                  // B*H*S*8 = 524288 floats each
    float* kh  = ws + 524288;
    float* vh  = ws + 1048576;
    float* hid = ws + 1572864;        // B*S*E = 524288 floats

    k_qkvq<<<dim3(256, 3), 256, 0, stream>>>(x, Wq, bq, Wk, bk, Wv, bv,
                                             theta, qh, kh, vh);
    k_attn<<<256, 256, 0, stream>>>(qh, kh, vh, hid);
    k_out <<<256, 256, 0, stream>>>(hid, Wo, bo, out);
}